// Round 13
// baseline (317.150 us; speedup 1.0000x reference)
//
#include <hip/hip_runtime.h>
#include <hip/hip_bf16.h>

#define NF     128
#define BATCH  64
#define NNODES 4096
#define MROWS  (BATCH * NNODES)       // 262144
#define NEDGE  (BATCH * (NNODES - 1)) // 262080
#define LN_EPS 1e-5f

typedef short  short8  __attribute__((ext_vector_type(8)));
typedef float  float4v __attribute__((ext_vector_type(4)));

__device__ __forceinline__ unsigned short f2bf(float f) {
    union { float f; unsigned u; } v; v.f = f;
    unsigned r = v.u;
    r = r + 0x7FFF + ((r >> 16) & 1);   // RNE
    return (unsigned short)(r >> 16);
}
__device__ __forceinline__ float bf2f(unsigned short b) {
    union { unsigned u; float f; } v; v.u = ((unsigned)b) << 16;
    return v.f;
}
// packed f32x2 -> bf16x2 (v_cvt_pk_bf16_f32), low short = lo. RNE == f2bf.
__device__ __forceinline__ unsigned pkbf(float lo, float hi) {
    __hip_bfloat162 h = __float22bfloat162_rn(float2{lo, hi});
    union { __hip_bfloat162 h; unsigned u; } v; v.h = h;
    return v.u;
}

// DPP 16-lane sum (VALU pipe, no LDS). Exact for aligned 16-lane groups.
template <int CTRL>
__device__ __forceinline__ float dppadd(float v) {
    union { float f; int i; } a, b; a.f = v;
    b.i = __builtin_amdgcn_mov_dpp(a.i, CTRL, 0xF, 0xF, true);
    return v + b.f;
}
__device__ __forceinline__ float red16(float v) {
    v = dppadd<0xB1>(v);    // quad_perm ^1
    v = dppadd<0x4E>(v);    // quad_perm ^2
    v = dppadd<0x141>(v);   // row_half_mirror
    v = dppadd<0x140>(v);   // row_mirror
    return v;
}

// A-fragment slot address (shorts): slot(q,m) holds A[m][k-octet q] (16 B).
__device__ __forceinline__ int slotAddr(int q, int m) {
    return ((q * 16 + m) ^ (q & 7)) * 8;
}

// r9 CONFLICT-FREE weight staging (verified: SQ_LDS_BANK_CONFLICT -> 0).
//   slot = group*64 + inner; group = (n>>4)*4 + s; inner = q*16 + (n&15)
//   !PERM: k = s*32 + q*8 + j     PERM: k = j*16 + s*4 + q
template <bool PERM, int NT>
__device__ __forceinline__ void stage_wfrags(const float* __restrict__ W,
                                             unsigned short* __restrict__ WF,
                                             int tid) {
    #pragma unroll
    for (int it = 0; it < (2048 + NT - 1) / NT; ++it) {
        int slot = tid + NT * it;            // 0..2047
        if (slot < 2048) {
            int inner = slot & 63;
            int group = slot >> 6;
            int s  = group & 3;
            int nh = group >> 2;             // n high nibble 0..15
            int nl = inner & 15;
            int q  = inner >> 4;
            int n  = nh * 16 + nl;
            union { unsigned short sh[8]; uint4 u; } tmp;
            #pragma unroll
            for (int j = 0; j < 8; ++j) {
                int k = PERM ? (j * 16 + s * 4 + q) : (s * 32 + q * 8 + j);
                tmp.sh[j] = f2bf(W[k * NF + n]);
            }
            *(uint4*)&WF[slot * 8] = tmp.u;
        }
    }
}

// bias + LayerNorm(128) + ELU, params pre-hoisted in registers (fused12).
__device__ __forceinline__ void ln_elu_r(float4v acc[8], const float* __restrict__ bias,
                                         const float* __restrict__ gn,
                                         const float* __restrict__ bt) {
    #pragma unroll
    for (int r = 0; r < 4; ++r) {
        float s1 = 0.f, s2 = 0.f;
        #pragma unroll
        for (int c = 0; c < 8; ++c) {
            float t = acc[c][r] + bias[c];
            acc[c][r] = t;
            s1 += t; s2 += t * t;
        }
        s1 = red16(s1);
        s2 = red16(s2);
        float mu  = s1 * (1.0f / 128.0f);
        float var = s2 * (1.0f / 128.0f) - mu * mu;
        float rs  = rsqrtf(var + LN_EPS);
        #pragma unroll
        for (int c = 0; c < 8; ++c) {
            float y = (acc[c][r] - mu) * rs * gn[c] + bt[c];
            acc[c][r] = (y > 0.f) ? y : (__expf(y) - 1.0f);
        }
    }
}

// bias + LayerNorm(128) + ELU reading interleaved params from LDS (edge).
__device__ __forceinline__ void ln_elu(float4v acc[8], const float* __restrict__ PI,
                                       int lnm) {
    float bias[8], gn[8], bt[8];
    #pragma unroll
    for (int c = 0; c < 8; ++c) {
        float4v prm = *(const float4v*)&PI[(c * 16 + lnm) * 4];
        bias[c] = prm[0]; gn[c] = prm[1]; bt[c] = prm[2];
    }
    #pragma unroll
    for (int r = 0; r < 4; ++r) {
        float s1 = 0.f, s2 = 0.f;
        #pragma unroll
        for (int c = 0; c < 8; ++c) {
            float t = acc[c][r] + bias[c];
            acc[c][r] = t;
            s1 += t; s2 += t * t;
        }
        s1 = red16(s1);
        s2 = red16(s2);
        float mu  = s1 * (1.0f / 128.0f);
        float var = s2 * (1.0f / 128.0f) - mu * mu;
        float rs  = rsqrtf(var + LN_EPS);
        #pragma unroll
        for (int c = 0; c < 8; ++c) {
            float y = (acc[c][r] - mu) * rs * gn[c] + bt[c];
            acc[c][r] = (y > 0.f) ? y : (__expf(y) - 1.0f);
        }
    }
}

// ---------------- fused layer1+layer2 ----------------
// r13: EXACT r10 kernel (best lineage: ~81 us, conflicts 0; r12 batching
// was neutral, dropped). TRIPWIRE: WRITE_SIZE 65536 KB; conflicts 0.
// LDS carve (shorts): WF1 [0,16384) | WF2 [16384,32768) |
//   MYF [32768, 32768+8*2048) | PI (floats) at 49152: 2 sets x 512 floats
#define F_MYF   32768
#define F_PI    49152
#define F_TOT   (49152 + 2048)          // shorts -> 102400 B

__global__ __launch_bounds__(512, 2)
void fused12_kernel(const float* __restrict__ x,
                    const float* __restrict__ W1, const float* __restrict__ b1,
                    const float* __restrict__ g1, const float* __restrict__ be1,
                    const float* __restrict__ W2, const float* __restrict__ b2,
                    const float* __restrict__ g2, const float* __restrict__ be2,
                    unsigned short* __restrict__ h2out)
{
    __shared__ __align__(16) unsigned short SH[F_TOT];

    const int tid  = threadIdx.x;
    const int lane = tid & 63;
    const int wave = tid >> 6;        // 0..7
    const int lnm  = lane & 15;
    const int qu   = lane >> 4;

    stage_wfrags<false, 512>(W1, &SH[0], tid);
    stage_wfrags<true,  512>(W2, &SH[16384], tid);
    float* PIf = (float*)&SH[F_PI];
    if (tid < NF) {
        PIf[tid * 4 + 0] = b1[tid]; PIf[tid * 4 + 1] = g1[tid]; PIf[tid * 4 + 2] = be1[tid];
        PIf[512 + tid * 4 + 0] = b2[tid]; PIf[512 + tid * 4 + 1] = g2[tid];
        PIf[512 + tid * 4 + 2] = be2[tid];
    }

    unsigned short* myF = &SH[F_MYF + wave * 2048];
    const unsigned short* WF1 = &SH[0];
    const unsigned short* WF2 = &SH[16384];

    const int nstrips = MROWS / 16;          // 16384
    const int sstep   = gridDim.x * 8;       // 2048 -> exactly 8 strips/wave
    int strip = blockIdx.x * 8 + wave;

    float4v rx[8];
    if (strip < nstrips) {
        const float* xs = x + (size_t)strip * (16 * NF);
        #pragma unroll
        for (int t = 0; t < 8; ++t)
            rx[t] = *(const float4v*)(xs + t * 256 + lane * 4);
    }
    __syncthreads();

    // hoist LN params for both layers into registers (48 VGPR; budget 256)
    float B1[8], G1[8], T1[8], B2[8], G2[8], T2[8];
    #pragma unroll
    for (int c = 0; c < 8; ++c) {
        float4v p1 = *(const float4v*)&PIf[(c * 16 + lnm) * 4];
        float4v p2 = *(const float4v*)&PIf[512 + (c * 16 + lnm) * 4];
        B1[c] = p1[0]; G1[c] = p1[1]; T1[c] = p1[2];
        B2[c] = p2[0]; G2[c] = p2[1]; T2[c] = p2[2];
    }

    const int qx = (lane & 31) >> 1;   // k-octet of this lane's x chunk
    const int hx = (lane & 1) * 4;     // half-slot offset (shorts)

    for (; strip < nstrips; strip += sstep) {
        const size_t rowBase = (size_t)strip * 16;

        // stage x (true feature order): rows t*2+(lane>>5), cols (lane&31)*4..+3
        #pragma unroll
        for (int t = 0; t < 8; ++t) {
            int m = t * 2 + (lane >> 5);
            uint2 u = { pkbf(rx[t][0], rx[t][1]), pkbf(rx[t][2], rx[t][3]) };
            *(uint2*)&myF[slotAddr(qx, m) + hx] = u;
        }
        // prefetch strip i+1 (in flight through all compute below)
        int sn = strip + sstep;
        if (sn < nstrips) {
            const float* xs = x + (size_t)sn * (16 * NF);
            #pragma unroll
            for (int t = 0; t < 8; ++t)
                rx[t] = *(const float4v*)(xs + t * 256 + lane * 4);
        }

        // layer 1 MFMA
        float4v acc[8];
        #pragma unroll
        for (int c = 0; c < 8; ++c) acc[c] = (float4v){0.f, 0.f, 0.f, 0.f};
        __builtin_amdgcn_s_setprio(1);
        #pragma unroll
        for (int s = 0; s < 4; ++s) {
            short8 af = *(const short8*)&myF[slotAddr(s * 4 + qu, lnm)];
            #pragma unroll
            for (int c = 0; c < 8; ++c) {
                short8 bfv = *(const short8*)&WF1[((c * 4 + s) * 64 + lane) * 8];
                acc[c] = __builtin_amdgcn_mfma_f32_16x16x32_bf16(af, bfv, acc[c], 0, 0, 0);
            }
        }
        __builtin_amdgcn_s_setprio(0);
        ln_elu_r(acc, B1, G1, T1);

        // L2 repack in PERMUTED feature order: lane's 8 c-values for row
        // m=qu*4+r are contiguous at positions lnm*8..+7 -> one b128 per r.
        // (LDS ops are in-order per wave: these writes can't pass the reads.)
        #pragma unroll
        for (int r = 0; r < 4; ++r) {
            uint4 u;
            u.x = pkbf(acc[0][r], acc[1][r]);
            u.y = pkbf(acc[2][r], acc[3][r]);
            u.z = pkbf(acc[4][r], acc[5][r]);
            u.w = pkbf(acc[6][r], acc[7][r]);
            *(uint4*)&myF[slotAddr(lnm, qu * 4 + r)] = u;
        }

        // layer 2 MFMA (WF2 staged with matching k-permutation)
        #pragma unroll
        for (int c = 0; c < 8; ++c) acc[c] = (float4v){0.f, 0.f, 0.f, 0.f};
        __builtin_amdgcn_s_setprio(1);
        #pragma unroll
        for (int s = 0; s < 4; ++s) {
            short8 af = *(const short8*)&myF[slotAddr(s * 4 + qu, lnm)];
            #pragma unroll
            for (int c = 0; c < 8; ++c) {
                short8 bfv = *(const short8*)&WF2[((c * 4 + s) * 64 + lane) * 8];
                acc[c] = __builtin_amdgcn_mfma_f32_16x16x32_bf16(af, bfv, acc[c], 0, 0, 0);
            }
        }
        __builtin_amdgcn_s_setprio(0);
        ln_elu_r(acc, B2, G2, T2);

        // store h2 DIRECTLY from registers in permuted feature layout.
        #pragma unroll
        for (int r = 0; r < 4; ++r) {
            uint4 u;
            u.x = pkbf(acc[0][r], acc[1][r]);
            u.y = pkbf(acc[2][r], acc[3][r]);
            u.z = pkbf(acc[4][r], acc[5][r]);
            u.w = pkbf(acc[6][r], acc[7][r]);
            *(uint4*)(h2out + (rowBase + qu * 4 + r) * NF + lnm * 8) = u;
        }
    }
}

// ---------------- edge kernel ----------------
// r13: 1024 THREADS (16 waves/CU, was 8). Edge is gather-latency-bound:
// parent reads are random 256-B segments over L3-resident 64 MB h2
// (~600-900 cyc); doubling waves/CU doubles outstanding gathers. r1's
// 1024-thr edge spilled at the 128-reg cap because the OLD body held 110+
// live regs; the current lean body (LDS LN params, batched weight reads)
// measured VGPR=88 <= 128 -> fits with no spill. launch_bounds(1024,4)
// declares the 128-reg cap explicitly. One staging per CU; LDS 98.5 KB.
// TRIPWIRE: edge WRITE_SIZE must stay ~1 MB (no spill).
// LDS carve: WFr [0,16384) | MYF [16384,16384+16*2048) | PI at 49152 shorts
#define E_MYF   16384
#define E_PI    49152
#define E_TOT   (49152 + 1024)          // shorts -> 100352 B

__global__ __launch_bounds__(1024, 4)
void edge_kernel(const unsigned short* __restrict__ h2,
                 const int* __restrict__ pidx,
                 const float* __restrict__ Wr1, const float* __restrict__ br1,
                 const float* __restrict__ gr1, const float* __restrict__ ber1,
                 const float* __restrict__ Wr2, const float* __restrict__ br2,
                 float* __restrict__ rout)
{
    __shared__ __align__(16) unsigned short SH[E_TOT];

    const int tid  = threadIdx.x;
    const int lane = tid & 63;
    const int wave = tid >> 6;        // 0..15
    const int lnm  = lane & 15;
    const int qu   = lane >> 4;

    stage_wfrags<true, 1024>(Wr1, &SH[0], tid);
    float* PIf = (float*)&SH[E_PI];
    if (tid < NF) {
        PIf[tid * 4 + 0] = br1[tid]; PIf[tid * 4 + 1] = gr1[tid];
        PIf[tid * 4 + 2] = ber1[tid];
    }

    float w2c[8];
    #pragma unroll
    for (int c = 0; c < 8; ++c) w2c[c] = Wr2[c * 16 + lnm];
    const float br2v = br2[0];

    unsigned short* myF = &SH[E_MYF + wave * 2048];
    const unsigned short* WFr = &SH[0];

    const int nstrips = NEDGE / 16;          // 16380
    const int sstep   = gridDim.x * 16;      // 4096 -> 3..4 strips/wave
    const int s0      = blockIdx.x * 16 + wave;

    short8 cv[4], pv[4];
    int prn[4];
    if (s0 < nstrips) {
        int pr[4];
        #pragma unroll
        for (int t = 0; t < 4; ++t) pr[t] = pidx[s0 * 16 + t * 4 + qu];
        #pragma unroll
        for (int t = 0; t < 4; ++t) {
            int e = s0 * 16 + t * 4 + qu;
            int crow = e + (int)((unsigned)e / 4095u);
            cv[t] = *(const short8*)(h2 + (size_t)crow * NF + lnm * 8);
            pv[t] = *(const short8*)(h2 + (size_t)pr[t] * NF + lnm * 8);
        }
        int s1 = s0 + sstep;
        if (s1 < nstrips) {
            #pragma unroll
            for (int t = 0; t < 4; ++t) prn[t] = pidx[s1 * 16 + t * 4 + qu];
        }
    }
    __syncthreads();

    for (int strip = s0; strip < nstrips; strip += sstep) {
        // max in fp32, pack pairs, one b128 slot write per t
        #pragma unroll
        for (int t = 0; t < 4; ++t) {
            float m0 = fmaxf(bf2f((unsigned short)cv[t][0]), bf2f((unsigned short)pv[t][0]));
            float m1 = fmaxf(bf2f((unsigned short)cv[t][1]), bf2f((unsigned short)pv[t][1]));
            float m2 = fmaxf(bf2f((unsigned short)cv[t][2]), bf2f((unsigned short)pv[t][2]));
            float m3 = fmaxf(bf2f((unsigned short)cv[t][3]), bf2f((unsigned short)pv[t][3]));
            float m4 = fmaxf(bf2f((unsigned short)cv[t][4]), bf2f((unsigned short)pv[t][4]));
            float m5 = fmaxf(bf2f((unsigned short)cv[t][5]), bf2f((unsigned short)pv[t][5]));
            float m6 = fmaxf(bf2f((unsigned short)cv[t][6]), bf2f((unsigned short)pv[t][6]));
            float m7 = fmaxf(bf2f((unsigned short)cv[t][7]), bf2f((unsigned short)pv[t][7]));
            uint4 u;
            u.x = pkbf(m0, m1); u.y = pkbf(m2, m3);
            u.z = pkbf(m4, m5); u.w = pkbf(m6, m7);
            *(uint4*)&myF[slotAddr(lnm, t * 4 + qu)] = u;
        }

        // prefetch next strip's rows (pidx already in prn), pidx two ahead
        int sn = strip + sstep;
        if (sn < nstrips) {
            #pragma unroll
            for (int t = 0; t < 4; ++t) {
                int e = sn * 16 + t * 4 + qu;
                int crow = e + (int)((unsigned)e / 4095u);
                cv[t] = *(const short8*)(h2 + (size_t)crow * NF + lnm * 8);
                pv[t] = *(const short8*)(h2 + (size_t)prn[t] * NF + lnm * 8);
            }
            int sn2 = sn + sstep;
            if (sn2 < nstrips) {
                #pragma unroll
                for (int t = 0; t < 4; ++t) prn[t] = pidx[sn2 * 16 + t * 4 + qu];
            }
        }

        // MFMA (batched B-frag reads) + LN/ELU + dot(Wr2)
        float4v acc[8];
        #pragma unroll
        for (int c = 0; c < 8; ++c) acc[c] = (float4v){0.f, 0.f, 0.f, 0.f};
        __builtin_amdgcn_s_setprio(1);
        #pragma unroll
        for (int s = 0; s < 4; ++s) {
            short8 af = *(const short8*)&myF[slotAddr(s * 4 + qu, lnm)];
            short8 bf[8];
            #pragma unroll
            for (int c = 0; c < 8; ++c)
                bf[c] = *(const short8*)&WFr[((c * 4 + s) * 64 + lane) * 8];
            #pragma unroll
            for (int c = 0; c < 8; ++c)
                acc[c] = __builtin_amdgcn_mfma_f32_16x16x32_bf16(af, bf[c], acc[c], 0, 0, 0);
        }
        __builtin_amdgcn_s_setprio(0);
        ln_elu(acc, PIf, lnm);

        #pragma unroll
        for (int r = 0; r < 4; ++r) {
            float t2 = 0.f;
            #pragma unroll
            for (int c = 0; c < 8; ++c) t2 += acc[c][r] * w2c[c];
            t2 = red16(t2);
            if (lnm == 0) rout[strip * 16 + qu * 4 + r] = t2 + br2v;
        }
    }
}

// lse: wave shfl reductions + 2 barriers per phase.
__global__ __launch_bounds__(1024)
void lse_kernel(const float* __restrict__ r, float* __restrict__ out)
{
    __shared__ float red[16];
    const int b = blockIdx.x;
    const float* rb = r + (size_t)b * 4095;
    const int tid  = threadIdx.x;
    const int lane = tid & 63;
    const int wv   = tid >> 6;     // 0..15

    float mx = -1e30f;
    for (int i = tid; i < 4095; i += 1024) mx = fmaxf(mx, rb[i]);
    #pragma unroll
    for (int o = 32; o; o >>= 1) mx = fmaxf(mx, __shfl_xor(mx, o, 64));
    if (lane == 0) red[wv] = mx;
    __syncthreads();
    #pragma unroll
    for (int w = 0; w < 16; ++w) mx = fmaxf(mx, red[w]);

    float sum = 0.f;
    for (int i = tid; i < 4095; i += 1024) sum += __expf(rb[i] - mx);
    #pragma unroll
    for (int o = 32; o; o >>= 1) sum += __shfl_xor(sum, o, 64);
    __syncthreads();
    if (lane == 0) red[wv] = sum;
    __syncthreads();
    sum = 0.f;
    #pragma unroll
    for (int w = 0; w < 16; ++w) sum += red[w];

    float lse = mx + __logf(sum);
    for (int i = tid; i < 4095; i += 1024)
        out[(size_t)b * 4095 + i] = rb[i] - lse;
}

extern "C" void kernel_launch(void* const* d_in, const int* in_sizes, int n_in,
                              void* d_out, int out_size, void* d_ws, size_t ws_size,
                              hipStream_t stream)
{
    const float* x    = (const float*)d_in[0];
    const int*   pidx = (const int*)d_in[1];
    const float* W1   = (const float*)d_in[2];
    const float* b1   = (const float*)d_in[3];
    const float* g1   = (const float*)d_in[4];
    const float* be1  = (const float*)d_in[5];
    const float* W2   = (const float*)d_in[6];
    const float* b2   = (const float*)d_in[7];
    const float* g2   = (const float*)d_in[8];
    const float* be2  = (const float*)d_in[9];
    const float* Wr1  = (const float*)d_in[10];
    const float* br1  = (const float*)d_in[11];
    const float* gr1  = (const float*)d_in[12];
    const float* ber1 = (const float*)d_in[13];
    const float* Wr2  = (const float*)d_in[14];
    const float* br2  = (const float*)d_in[15];
    float* out = (float*)d_out;

    // workspace: h2 (bf16, 64 MiB, permuted feature layout) | rbuf (fp32)
    unsigned short* h2 = (unsigned short*)d_ws;
    float* rbuf = (float*)(h2 + (size_t)MROWS * NF);

    fused12_kernel<<<256, 512, 0, stream>>>(x, W1, b1, g1, be1,
                                            W2, b2, g2, be2, h2);
    edge_kernel<<<256, 1024, 0, stream>>>(h2, pidx, Wr1, br1, gr1, ber1,
                                          Wr2, br2, rbuf);
    lse_kernel<<<BATCH, 1024, 0, stream>>>(rbuf, out);
}

// Round 14
// 273.311 us; speedup vs baseline: 1.1604x; 1.1604x over previous
//
#include <hip/hip_runtime.h>
#include <hip/hip_bf16.h>

#define NF     128
#define BATCH  64
#define NNODES 4096
#define MROWS  (BATCH * NNODES)       // 262144
#define NEDGE  (BATCH * (NNODES - 1)) // 262080
#define LN_EPS 1e-5f

typedef short  short8  __attribute__((ext_vector_type(8)));
typedef float  float4v __attribute__((ext_vector_type(4)));

__device__ __forceinline__ unsigned short f2bf(float f) {
    union { float f; unsigned u; } v; v.f = f;
    unsigned r = v.u;
    r = r + 0x7FFF + ((r >> 16) & 1);   // RNE
    return (unsigned short)(r >> 16);
}
__device__ __forceinline__ float bf2f(unsigned short b) {
    union { unsigned u; float f; } v; v.u = ((unsigned)b) << 16;
    return v.f;
}
// packed f32x2 -> bf16x2 (v_cvt_pk_bf16_f32), low short = lo. RNE == f2bf.
__device__ __forceinline__ unsigned pkbf(float lo, float hi) {
    __hip_bfloat162 h = __float22bfloat162_rn(float2{lo, hi});
    union { __hip_bfloat162 h; unsigned u; } v; v.h = h;
    return v.u;
}

// DPP 16-lane sum (VALU pipe, no LDS). Exact for aligned 16-lane groups.
template <int CTRL>
__device__ __forceinline__ float dppadd(float v) {
    union { float f; int i; } a, b; a.f = v;
    b.i = __builtin_amdgcn_mov_dpp(a.i, CTRL, 0xF, 0xF, true);
    return v + b.f;
}
__device__ __forceinline__ float red16(float v) {
    v = dppadd<0xB1>(v);    // quad_perm ^1
    v = dppadd<0x4E>(v);    // quad_perm ^2
    v = dppadd<0x141>(v);   // row_half_mirror
    v = dppadd<0x140>(v);   // row_mirror
    return v;
}

// A-fragment slot address (shorts): slot(q,m) holds A[m][k-octet q] (16 B).
__device__ __forceinline__ int slotAddr(int q, int m) {
    return ((q * 16 + m) ^ (q & 7)) * 8;
}

// r9 CONFLICT-FREE weight staging (verified: SQ_LDS_BANK_CONFLICT -> 0).
//   slot = group*64 + inner; group = (n>>4)*4 + s; inner = q*16 + (n&15)
//   !PERM: k = s*32 + q*8 + j     PERM: k = j*16 + s*4 + q
template <bool PERM, int NT>
__device__ __forceinline__ void stage_wfrags(const float* __restrict__ W,
                                             unsigned short* __restrict__ WF,
                                             int tid) {
    #pragma unroll
    for (int it = 0; it < (2048 + NT - 1) / NT; ++it) {
        int slot = tid + NT * it;            // 0..2047
        if (slot < 2048) {
            int inner = slot & 63;
            int group = slot >> 6;
            int s  = group & 3;
            int nh = group >> 2;             // n high nibble 0..15
            int nl = inner & 15;
            int q  = inner >> 4;
            int n  = nh * 16 + nl;
            union { unsigned short sh[8]; uint4 u; } tmp;
            #pragma unroll
            for (int j = 0; j < 8; ++j) {
                int k = PERM ? (j * 16 + s * 4 + q) : (s * 32 + q * 8 + j);
                tmp.sh[j] = f2bf(W[k * NF + n]);
            }
            *(uint4*)&WF[slot * 8] = tmp.u;
        }
    }
}

// bias + LayerNorm(128) + ELU, params pre-hoisted in registers (fused12).
__device__ __forceinline__ void ln_elu_r(float4v acc[8], const float* __restrict__ bias,
                                         const float* __restrict__ gn,
                                         const float* __restrict__ bt) {
    #pragma unroll
    for (int r = 0; r < 4; ++r) {
        float s1 = 0.f, s2 = 0.f;
        #pragma unroll
        for (int c = 0; c < 8; ++c) {
            float t = acc[c][r] + bias[c];
            acc[c][r] = t;
            s1 += t; s2 += t * t;
        }
        s1 = red16(s1);
        s2 = red16(s2);
        float mu  = s1 * (1.0f / 128.0f);
        float var = s2 * (1.0f / 128.0f) - mu * mu;
        float rs  = rsqrtf(var + LN_EPS);
        #pragma unroll
        for (int c = 0; c < 8; ++c) {
            float y = (acc[c][r] - mu) * rs * gn[c] + bt[c];
            acc[c][r] = (y > 0.f) ? y : (__expf(y) - 1.0f);
        }
    }
}

// bias + LayerNorm(128) + ELU reading interleaved params from LDS (edge).
__device__ __forceinline__ void ln_elu(float4v acc[8], const float* __restrict__ PI,
                                       int lnm) {
    float bias[8], gn[8], bt[8];
    #pragma unroll
    for (int c = 0; c < 8; ++c) {
        float4v prm = *(const float4v*)&PI[(c * 16 + lnm) * 4];
        bias[c] = prm[0]; gn[c] = prm[1]; bt[c] = prm[2];
    }
    #pragma unroll
    for (int r = 0; r < 4; ++r) {
        float s1 = 0.f, s2 = 0.f;
        #pragma unroll
        for (int c = 0; c < 8; ++c) {
            float t = acc[c][r] + bias[c];
            acc[c][r] = t;
            s1 += t; s2 += t * t;
        }
        s1 = red16(s1);
        s2 = red16(s2);
        float mu  = s1 * (1.0f / 128.0f);
        float var = s2 * (1.0f / 128.0f) - mu * mu;
        float rs  = rsqrtf(var + LN_EPS);
        #pragma unroll
        for (int c = 0; c < 8; ++c) {
            float y = (acc[c][r] - mu) * rs * gn[c] + bt[c];
            acc[c][r] = (y > 0.f) ? y : (__expf(y) - 1.0f);
        }
    }
}

// ---------------- fused layer1+layer2 ----------------
// r14: r10 body + PER-WAVE DOUBLE-BUFFERED myF. The r6 cycle accounting
// closes on: per-strip serial chain ~1.5k cyc x 8 strips = the 12.5k wall.
// Successive strips can't overlap because strip i+1's stage writes hit the
// SAME myF addresses strip i's L2-MFMA reads (WAR through the single
// buffer). Double-buffer (2x2048 shorts/wave) + stage-next-at-end-of-body:
// the ds_writes for i+1 complete under the h2 store + next L1 window.
// Zero register cost (one XOR'd offset). LDS 135168 B -> still 1 block/CU.
// All waves do exactly 8 strips -> guards are wave-uniform (no divergence).
// TRIPWIRE: WRITE_SIZE 65536 KB exactly; conflicts 0.
// LDS carve (shorts): WF1 [0,16384) | WF2 [16384,32768) |
//   MYF [32768, 32768+8*4096) | PI (floats) at 65536: 2 sets x 512 floats
#define F_MYF   32768
#define F_PI    65536
#define F_TOT   (65536 + 2048)          // shorts -> 135168 B

__global__ __launch_bounds__(512, 2)
void fused12_kernel(const float* __restrict__ x,
                    const float* __restrict__ W1, const float* __restrict__ b1,
                    const float* __restrict__ g1, const float* __restrict__ be1,
                    const float* __restrict__ W2, const float* __restrict__ b2,
                    const float* __restrict__ g2, const float* __restrict__ be2,
                    unsigned short* __restrict__ h2out)
{
    __shared__ __align__(16) unsigned short SH[F_TOT];

    const int tid  = threadIdx.x;
    const int lane = tid & 63;
    const int wave = tid >> 6;        // 0..7
    const int lnm  = lane & 15;
    const int qu   = lane >> 4;

    stage_wfrags<false, 512>(W1, &SH[0], tid);
    stage_wfrags<true,  512>(W2, &SH[16384], tid);
    float* PIf = (float*)&SH[F_PI];
    if (tid < NF) {
        PIf[tid * 4 + 0] = b1[tid]; PIf[tid * 4 + 1] = g1[tid]; PIf[tid * 4 + 2] = be1[tid];
        PIf[512 + tid * 4 + 0] = b2[tid]; PIf[512 + tid * 4 + 1] = g2[tid];
        PIf[512 + tid * 4 + 2] = be2[tid];
    }

    unsigned short* myF = &SH[F_MYF + wave * 4096];   // two 2048-short bufs
    const unsigned short* WF1 = &SH[0];
    const unsigned short* WF2 = &SH[16384];

    const int nstrips = MROWS / 16;          // 16384
    const int sstep   = gridDim.x * 8;       // 2048 -> exactly 8 strips/wave
    int strip = blockIdx.x * 8 + wave;

    float4v rx[8];
    if (strip < nstrips) {
        const float* xs = x + (size_t)strip * (16 * NF);
        #pragma unroll
        for (int t = 0; t < 8; ++t)
            rx[t] = *(const float4v*)(xs + t * 256 + lane * 4);
    }
    __syncthreads();

    // hoist LN params for both layers into registers (48 VGPR; budget 256)
    float B1[8], G1[8], T1[8], B2[8], G2[8], T2[8];
    #pragma unroll
    for (int c = 0; c < 8; ++c) {
        float4v p1 = *(const float4v*)&PIf[(c * 16 + lnm) * 4];
        float4v p2 = *(const float4v*)&PIf[512 + (c * 16 + lnm) * 4];
        B1[c] = p1[0]; G1[c] = p1[1]; T1[c] = p1[2];
        B2[c] = p2[0]; G2[c] = p2[1]; T2[c] = p2[2];
    }

    const int qx = (lane & 31) >> 1;   // k-octet of this lane's x chunk
    const int hx = (lane & 1) * 4;     // half-slot offset (shorts)

    // prologue: stage strip 0 into buf 0; prefetch strip 1
    int moff = 0;
    if (strip < nstrips) {
        #pragma unroll
        for (int t = 0; t < 8; ++t) {
            int m = t * 2 + (lane >> 5);
            uint2 u = { pkbf(rx[t][0], rx[t][1]), pkbf(rx[t][2], rx[t][3]) };
            *(uint2*)&myF[slotAddr(qx, m) + hx] = u;
        }
        int sn = strip + sstep;
        if (sn < nstrips) {
            const float* xs = x + (size_t)sn * (16 * NF);
            #pragma unroll
            for (int t = 0; t < 8; ++t)
                rx[t] = *(const float4v*)(xs + t * 256 + lane * 4);
        }
    }

    for (; strip < nstrips; strip += sstep) {
        const size_t rowBase = (size_t)strip * 16;
        unsigned short* mb = myF + moff;

        // layer 1 MFMA (A staged in mb by previous iteration / prologue)
        float4v acc[8];
        #pragma unroll
        for (int c = 0; c < 8; ++c) acc[c] = (float4v){0.f, 0.f, 0.f, 0.f};
        __builtin_amdgcn_s_setprio(1);
        #pragma unroll
        for (int s = 0; s < 4; ++s) {
            short8 af = *(const short8*)&mb[slotAddr(s * 4 + qu, lnm)];
            #pragma unroll
            for (int c = 0; c < 8; ++c) {
                short8 bfv = *(const short8*)&WF1[((c * 4 + s) * 64 + lane) * 8];
                acc[c] = __builtin_amdgcn_mfma_f32_16x16x32_bf16(af, bfv, acc[c], 0, 0, 0);
            }
        }
        __builtin_amdgcn_s_setprio(0);
        ln_elu_r(acc, B1, G1, T1);

        // L2 repack in PERMUTED feature order (in-order LDS: these writes
        // can't pass the L1 reads above)
        #pragma unroll
        for (int r = 0; r < 4; ++r) {
            uint4 u;
            u.x = pkbf(acc[0][r], acc[1][r]);
            u.y = pkbf(acc[2][r], acc[3][r]);
            u.z = pkbf(acc[4][r], acc[5][r]);
            u.w = pkbf(acc[6][r], acc[7][r]);
            *(uint4*)&mb[slotAddr(lnm, qu * 4 + r)] = u;
        }

        // layer 2 MFMA (WF2 staged with matching k-permutation)
        #pragma unroll
        for (int c = 0; c < 8; ++c) acc[c] = (float4v){0.f, 0.f, 0.f, 0.f};
        __builtin_amdgcn_s_setprio(1);
        #pragma unroll
        for (int s = 0; s < 4; ++s) {
            short8 af = *(const short8*)&mb[slotAddr(s * 4 + qu, lnm)];
            #pragma unroll
            for (int c = 0; c < 8; ++c) {
                short8 bfv = *(const short8*)&WF2[((c * 4 + s) * 64 + lane) * 8];
                acc[c] = __builtin_amdgcn_mfma_f32_16x16x32_bf16(af, bfv, acc[c], 0, 0, 0);
            }
        }
        __builtin_amdgcn_s_setprio(0);
        ln_elu_r(acc, B2, G2, T2);

        // stage strip i+1 into the ALTERNATE buffer (rx holds its data) --
        // overlaps with the h2 store below and next iteration's L1 wait.
        int sn = strip + sstep;
        if (sn < nstrips) {
            unsigned short* mb2 = myF + (moff ^ 2048);
            #pragma unroll
            for (int t = 0; t < 8; ++t) {
                int m = t * 2 + (lane >> 5);
                uint2 u = { pkbf(rx[t][0], rx[t][1]), pkbf(rx[t][2], rx[t][3]) };
                *(uint2*)&mb2[slotAddr(qx, m) + hx] = u;
            }
            int sn2 = strip + 2 * sstep;
            if (sn2 < nstrips) {
                const float* xs = x + (size_t)sn2 * (16 * NF);
                #pragma unroll
                for (int t = 0; t < 8; ++t)
                    rx[t] = *(const float4v*)(xs + t * 256 + lane * 4);
            }
        }

        // store h2 DIRECTLY from registers in permuted feature layout.
        #pragma unroll
        for (int r = 0; r < 4; ++r) {
            uint4 u;
            u.x = pkbf(acc[0][r], acc[1][r]);
            u.y = pkbf(acc[2][r], acc[3][r]);
            u.z = pkbf(acc[4][r], acc[5][r]);
            u.w = pkbf(acc[6][r], acc[7][r]);
            *(uint4*)(h2out + (rowBase + qu * 4 + r) * NF + lnm * 8) = u;
        }

        moff ^= 2048;
    }
}

// ---------------- edge kernel ----------------
// r14: EXACT r10 edge (best measured config ~47 us: r7 body + conflict-free
// staging, 512 thr, grid 256). r13 proved 1024-thr spills (allocator splits
// the 128-reg budget 64/64 unconditionally) -- occupancy is pinned at
// 8 waves/CU for any MFMA body here.
// LDS carve: WFr [0,16384) | MYF [16384,16384+8*2048) | PI at 32768 shorts
#define E_MYF   16384
#define E_PI    32768
#define E_TOT   (32768 + 1024)          // shorts -> 67584 B

__global__ __launch_bounds__(512, 2)
void edge_kernel(const unsigned short* __restrict__ h2,
                 const int* __restrict__ pidx,
                 const float* __restrict__ Wr1, const float* __restrict__ br1,
                 const float* __restrict__ gr1, const float* __restrict__ ber1,
                 const float* __restrict__ Wr2, const float* __restrict__ br2,
                 float* __restrict__ rout)
{
    __shared__ __align__(16) unsigned short SH[E_TOT];

    const int tid  = threadIdx.x;
    const int lane = tid & 63;
    const int wave = tid >> 6;        // 0..7
    const int lnm  = lane & 15;
    const int qu   = lane >> 4;

    stage_wfrags<true, 512>(Wr1, &SH[0], tid);
    float* PIf = (float*)&SH[E_PI];
    if (tid < NF) {
        PIf[tid * 4 + 0] = br1[tid]; PIf[tid * 4 + 1] = gr1[tid];
        PIf[tid * 4 + 2] = ber1[tid];
    }

    float w2c[8];
    #pragma unroll
    for (int c = 0; c < 8; ++c) w2c[c] = Wr2[c * 16 + lnm];
    const float br2v = br2[0];

    unsigned short* myF = &SH[E_MYF + wave * 2048];
    const unsigned short* WFr = &SH[0];

    const int nstrips = NEDGE / 16;          // 16380
    const int sstep   = gridDim.x * 8;       // 2048 -> 7..8 strips/wave
    const int s0      = blockIdx.x * 8 + wave;

    short8 cv[4], pv[4];
    int prn[4];
    if (s0 < nstrips) {
        int pr[4];
        #pragma unroll
        for (int t = 0; t < 4; ++t) pr[t] = pidx[s0 * 16 + t * 4 + qu];
        #pragma unroll
        for (int t = 0; t < 4; ++t) {
            int e = s0 * 16 + t * 4 + qu;
            int crow = e + (int)((unsigned)e / 4095u);
            cv[t] = *(const short8*)(h2 + (size_t)crow * NF + lnm * 8);
            pv[t] = *(const short8*)(h2 + (size_t)pr[t] * NF + lnm * 8);
        }
        int s1 = s0 + sstep;
        if (s1 < nstrips) {
            #pragma unroll
            for (int t = 0; t < 4; ++t) prn[t] = pidx[s1 * 16 + t * 4 + qu];
        }
    }
    __syncthreads();

    for (int strip = s0; strip < nstrips; strip += sstep) {
        // max in fp32, pack pairs, one b128 slot write per t
        #pragma unroll
        for (int t = 0; t < 4; ++t) {
            float m0 = fmaxf(bf2f((unsigned short)cv[t][0]), bf2f((unsigned short)pv[t][0]));
            float m1 = fmaxf(bf2f((unsigned short)cv[t][1]), bf2f((unsigned short)pv[t][1]));
            float m2 = fmaxf(bf2f((unsigned short)cv[t][2]), bf2f((unsigned short)pv[t][2]));
            float m3 = fmaxf(bf2f((unsigned short)cv[t][3]), bf2f((unsigned short)pv[t][3]));
            float m4 = fmaxf(bf2f((unsigned short)cv[t][4]), bf2f((unsigned short)pv[t][4]));
            float m5 = fmaxf(bf2f((unsigned short)cv[t][5]), bf2f((unsigned short)pv[t][5]));
            float m6 = fmaxf(bf2f((unsigned short)cv[t][6]), bf2f((unsigned short)pv[t][6]));
            float m7 = fmaxf(bf2f((unsigned short)cv[t][7]), bf2f((unsigned short)pv[t][7]));
            uint4 u;
            u.x = pkbf(m0, m1); u.y = pkbf(m2, m3);
            u.z = pkbf(m4, m5); u.w = pkbf(m6, m7);
            *(uint4*)&myF[slotAddr(lnm, t * 4 + qu)] = u;
        }

        // prefetch next strip's rows (pidx already in prn), pidx two ahead
        int sn = strip + sstep;
        if (sn < nstrips) {
            #pragma unroll
            for (int t = 0; t < 4; ++t) {
                int e = sn * 16 + t * 4 + qu;
                int crow = e + (int)((unsigned)e / 4095u);
                cv[t] = *(const short8*)(h2 + (size_t)crow * NF + lnm * 8);
                pv[t] = *(const short8*)(h2 + (size_t)prn[t] * NF + lnm * 8);
            }
            int sn2 = sn + sstep;
            if (sn2 < nstrips) {
                #pragma unroll
                for (int t = 0; t < 4; ++t) prn[t] = pidx[sn2 * 16 + t * 4 + qu];
            }
        }

        // MFMA (batched B-frag reads) + LN/ELU + dot(Wr2)
        float4v acc[8];
        #pragma unroll
        for (int c = 0; c < 8; ++c) acc[c] = (float4v){0.f, 0.f, 0.f, 0.f};
        __builtin_amdgcn_s_setprio(1);
        #pragma unroll
        for (int s = 0; s < 4; ++s) {
            short8 af = *(const short8*)&myF[slotAddr(s * 4 + qu, lnm)];
            short8 bf[8];
            #pragma unroll
            for (int c = 0; c < 8; ++c)
                bf[c] = *(const short8*)&WFr[((c * 4 + s) * 64 + lane) * 8];
            #pragma unroll
            for (int c = 0; c < 8; ++c)
                acc[c] = __builtin_amdgcn_mfma_f32_16x16x32_bf16(af, bf[c], acc[c], 0, 0, 0);
        }
        __builtin_amdgcn_s_setprio(0);
        ln_elu(acc, PIf, lnm);

        #pragma unroll
        for (int r = 0; r < 4; ++r) {
            float t2 = 0.f;
            #pragma unroll
            for (int c = 0; c < 8; ++c) t2 += acc[c][r] * w2c[c];
            t2 = red16(t2);
            if (lnm == 0) rout[strip * 16 + qu * 4 + r] = t2 + br2v;
        }
    }
}

// lse: wave shfl reductions + 2 barriers per phase.
__global__ __launch_bounds__(1024)
void lse_kernel(const float* __restrict__ r, float* __restrict__ out)
{
    __shared__ float red[16];
    const int b = blockIdx.x;
    const float* rb = r + (size_t)b * 4095;
    const int tid  = threadIdx.x;
    const int lane = tid & 63;
    const int wv   = tid >> 6;     // 0..15

    float mx = -1e30f;
    for (int i = tid; i < 4095; i += 1024) mx = fmaxf(mx, rb[i]);
    #pragma unroll
    for (int o = 32; o; o >>= 1) mx = fmaxf(mx, __shfl_xor(mx, o, 64));
    if (lane == 0) red[wv] = mx;
    __syncthreads();
    #pragma unroll
    for (int w = 0; w < 16; ++w) mx = fmaxf(mx, red[w]);

    float sum = 0.f;
    for (int i = tid; i < 4095; i += 1024) sum += __expf(rb[i] - mx);
    #pragma unroll
    for (int o = 32; o; o >>= 1) sum += __shfl_xor(sum, o, 64);
    __syncthreads();
    if (lane == 0) red[wv] = sum;
    __syncthreads();
    sum = 0.f;
    #pragma unroll
    for (int w = 0; w < 16; ++w) sum += red[w];

    float lse = mx + __logf(sum);
    for (int i = tid; i < 4095; i += 1024)
        out[(size_t)b * 4095 + i] = rb[i] - lse;
}

extern "C" void kernel_launch(void* const* d_in, const int* in_sizes, int n_in,
                              void* d_out, int out_size, void* d_ws, size_t ws_size,
                              hipStream_t stream)
{
    const float* x    = (const float*)d_in[0];
    const int*   pidx = (const int*)d_in[1];
    const float* W1   = (const float*)d_in[2];
    const float* b1   = (const float*)d_in[3];
    const float* g1   = (const float*)d_in[4];
    const float* be1  = (const float*)d_in[5];
    const float* W2   = (const float*)d_in[6];
    const float* b2   = (const float*)d_in[7];
    const float* g2   = (const float*)d_in[8];
    const float* be2  = (const float*)d_in[9];
    const float* Wr1  = (const float*)d_in[10];
    const float* br1  = (const float*)d_in[11];
    const float* gr1  = (const float*)d_in[12];
    const float* ber1 = (const float*)d_in[13];
    const float* Wr2  = (const float*)d_in[14];
    const float* br2  = (const float*)d_in[15];
    float* out = (float*)d_out;

    // workspace: h2 (bf16, 64 MiB, permuted feature layout) | rbuf (fp32)
    unsigned short* h2 = (unsigned short*)d_ws;
    float* rbuf = (float*)(h2 + (size_t)MROWS * NF);

    fused12_kernel<<<256, 512, 0, stream>>>(x, W1, b1, g1, be1,
                                            W2, b2, g2, be2, h2);
    edge_kernel<<<256, 512, 0, stream>>>(h2, pidx, Wr1, br1, gr1, ber1,
                                         Wr2, br2, rbuf);
    lse_kernel<<<BATCH, 1024, 0, stream>>>(rbuf, out);
}